// Round 21
// baseline (113.970 us; speedup 1.0000x reference)
//
#include <hip/hip_runtime.h>
#include <hip/hip_bf16.h>
#include <math.h>

#define N_NODES 100000
#define N_EDGES 1600000
#define IN_CH 256
#define HID_CH 32
#define OUT_CH 8
#define N_GRAPHS 64

// bucket sort params (128 nodes / bucket)
#define BUCK_SHIFT 7
#define NODES_PER_BUCK 128
#define NBUCK ((N_NODES + NODES_PER_BUCK - 1) / NODES_PER_BUCK)   // 782
#define CAP 2560
#define PCAP 3456
#define CHUNK 4096
#define NBLK_P1 ((N_EDGES + CHUNK - 1) / CHUNK)                   // 391
#define ARENA (NBUCK * CAP)

#define DUMMY_ROW N_NODES
#define Y_ROWS 100008

#define GEMM_TILES (N_NODES / 16)          // 6250
#define GEMM_BLKS ((GEMM_TILES + 3) / 4)   // 1563
#define POOL_BLKS (N_NODES / 32)           // 3125

// ---------------- workspace layout (in 4-byte words) ----------------
#define OFF_DEG    0
#define OFF_DINV   (OFF_DEG + N_NODES)
#define OFF_ROWS   (OFF_DINV + N_NODES)
#define OFF_CNTG   (OFF_ROWS + N_NODES)
#define OFF_CSR    (OFF_CNTG + 784)
#define OFF_Y1     (OFF_CSR + NBUCK*PCAP)           // fp8[Y_ROWS*32] = 8 words/row
#define OFF_BBUF   (OFF_Y1 + Y_ROWS*8)
#define OFF_Y2     (OFF_BBUF + ARENA)               // fp8[Y_ROWS*8]  = 2 words/row
#define OFF_PSUM   (OFF_Y2 + Y_ROWS*2)
#define OFF_PCNT   (OFF_PSUM + N_GRAPHS*OUT_CH)
#define OFF_WFRAG  (OFF_PCNT + 128)                 // 4096 words

typedef __attribute__((ext_vector_type(8))) short bf16x8;
typedef __attribute__((ext_vector_type(4))) float f32x4;
typedef __attribute__((ext_vector_type(2))) float f32x2;

__device__ __forceinline__ unsigned bfr(float f) {
    unsigned u = __float_as_uint(f);
    return (u + 0x7fffu + ((u >> 16) & 1u)) >> 16;
}
__device__ __forceinline__ float bf_lo(unsigned w) { return __uint_as_float(w << 16); }
__device__ __forceinline__ float bf_hi(unsigned w) { return __uint_as_float(w & 0xffff0000u); }

// accumulate 8 fp8 channels from a uint2 (bytes 0..7 = 8 consecutive channels)
#define ACC8F8(v) do { \
    const f32x2 q0 = __builtin_amdgcn_cvt_pk_f32_fp8((int)(v).x, false); \
    const f32x2 q1 = __builtin_amdgcn_cvt_pk_f32_fp8((int)(v).x, true);  \
    const f32x2 q2 = __builtin_amdgcn_cvt_pk_f32_fp8((int)(v).y, false); \
    const f32x2 q3 = __builtin_amdgcn_cvt_pk_f32_fp8((int)(v).y, true);  \
    a0 += q0.x; a1 += q0.y; a2 += q1.x; a3 += q1.y; \
    a4 += q2.x; a5 += q2.y; a6 += q3.x; a7 += q3.y; } while (0)

// wprep: pack W1 into MFMA B-frags; block 0 zeroes cntg + dummy rows.
__global__ __launch_bounds__(256) void wprep_kernel(
        const float* __restrict__ W1, uint4* __restrict__ wfrag,
        unsigned* __restrict__ cntg, unsigned* __restrict__ y1w,
        unsigned* __restrict__ y2w) {
    const int t = threadIdx.x;
    if (blockIdx.x == 0) {
        for (int i = t; i < NBUCK; i += 256) cntg[i] = 0u;
        if (t < 8) y1w[(size_t)DUMMY_ROW * 8 + t] = 0u;   // fp8 y1 row = 32B
        if (t < 2) y2w[(size_t)DUMMY_ROW * 2 + t] = 0u;   // fp8 y2 row = 8B
    }
    const int fl = blockIdx.x * 256 + t;
    const int f = fl >> 6, lane = fl & 63;
    const int kb = f >> 1, cb = f & 1;
    const int lr = lane & 15, lg = lane >> 4;
    unsigned short s[8];
#pragma unroll
    for (int j = 0; j < 8; j++)
        s[j] = (unsigned short)bfr(W1[(kb * 32 + lg * 8 + j) * 32 + cb * 16 + lr]);
    uint4 pk;
    pk.x = s[0] | ((unsigned)s[1] << 16);
    pk.y = s[2] | ((unsigned)s[3] << 16);
    pk.z = s[4] | ((unsigned)s[5] << 16);
    pk.w = s[6] | ((unsigned)s[7] << 16);
    wfrag[fl] = pk;
}

// p1: CHUNK=4096 (391 blocks); 16 edges staged per thread.
__global__ __launch_bounds__(256) void p1_partition(
        const int* __restrict__ src, const int* __restrict__ dst,
        unsigned* __restrict__ cntg, unsigned* __restrict__ bbuf) {
    __shared__ unsigned hcnt[NBUCK];
    __shared__ unsigned hcur[NBUCK];
    const int t = threadIdx.x;
    const long long e0 = (long long)blockIdx.x * CHUNK;

    int rs[16]; unsigned rd[16];
#pragma unroll
    for (int i = 0; i < 16; i++) {
        const long long e = e0 + t + i * 256;
        const bool v = (e < N_EDGES);
        rs[i] = v ? src[e] : 0;
        rd[i] = v ? (unsigned)dst[e] : 0xFFFFFFFFu;
    }
    for (int i = t; i < NBUCK; i += 256) hcnt[i] = 0;
    __syncthreads();
#pragma unroll
    for (int i = 0; i < 16; i++)
        if (rd[i] != 0xFFFFFFFFu) atomicAdd(&hcnt[rd[i] >> BUCK_SHIFT], 1u);
    __syncthreads();
    for (int i = t; i < NBUCK; i += 256) {
        const unsigned c = hcnt[i];
        const unsigned r = c ? atomicAdd(&cntg[i], c) : 0u;
        hcur[i] = (unsigned)i * CAP + r;
    }
    __syncthreads();
#pragma unroll
    for (int i = 0; i < 16; i++) {
        if (rd[i] != 0xFFFFFFFFu) {
            const unsigned b = rd[i] >> BUCK_SHIFT;
            const unsigned pos = atomicAdd(&hcur[b], 1u);
            if (pos - b * CAP < CAP)
                bbuf[pos] = (unsigned)rs[i] | ((rd[i] & (NODES_PER_BUCK - 1)) << 17);
        }
    }
}

__global__ __launch_bounds__(256) void p2_build(
        const unsigned* __restrict__ cntg,
        const unsigned* __restrict__ bbuf, int* __restrict__ csr,
        unsigned* __restrict__ deg, unsigned* __restrict__ rowstart,
        float* __restrict__ dinv) {
    __shared__ unsigned hist[NODES_PER_BUCK];
    __shared__ unsigned start[NODES_PER_BUCK];
    __shared__ unsigned cur[NODES_PER_BUCK];
    __shared__ unsigned s[256];
    __shared__ int lcsr[PCAP];
    const int b = blockIdx.x;
    const int t = threadIdx.x;
    unsigned cnt = cntg[b]; if (cnt > CAP) cnt = CAP;
    const unsigned* mybuf = bbuf + (size_t)b * CAP;

    if (t < NODES_PER_BUCK) hist[t] = 0;
    __syncthreads();
    for (unsigned i = t; i < cnt; i += 256) atomicAdd(&hist[mybuf[i] >> 17], 1u);
    __syncthreads();
    const unsigned d = (t < NODES_PER_BUCK) ? hist[t] : 0u;
    const unsigned pd = (d + 7u) & ~7u;
    s[t] = pd;
    __syncthreads();
    for (int off = 1; off < 256; off <<= 1) {
        unsigned x = (t >= off) ? s[t - off] : 0u;
        __syncthreads();
        s[t] += x;
        __syncthreads();
    }
    const unsigned total = s[255];
    const unsigned ex = s[t] - pd;
    if (t < NODES_PER_BUCK) { start[t] = ex; cur[t] = ex; }
    __syncthreads();
    for (unsigned i = t; i < total; i += 256) lcsr[i] = DUMMY_ROW;
    __syncthreads();
    for (unsigned i = t; i < cnt; i += 256) {
        const unsigned p = mybuf[i];
        const unsigned pos = atomicAdd(&cur[p >> 17], 1u);
        lcsr[pos] = (int)(p & 0x1FFFFu);
    }
    __syncthreads();
    const unsigned gbase = (unsigned)b * PCAP;
    for (unsigned i = t; i < total; i += 256) csr[gbase + i] = lcsr[i];
    const int n = b * NODES_PER_BUCK + t;
    if (t < NODES_PER_BUCK && n < N_NODES) {
        deg[n] = d;
        rowstart[n] = gbase + start[t];
        dinv[n] = rsqrtf((float)d + 1.0f);
    }
}

// y1 = fp8_e4m3((x @ W1) * dinv) via MFMA 16x16x32 bf16 — no LDS/barriers.
__global__ __launch_bounds__(256) void gemm1_kernel(
        const float* __restrict__ x, const uint4* __restrict__ wfrag,
        const float* __restrict__ dinv, unsigned char* __restrict__ y1f8,
        float* __restrict__ psum) {
    const int t = threadIdx.x;
    if (blockIdx.x == 0) {
        for (int i = t; i < N_GRAPHS * OUT_CH + N_GRAPHS; i += 256) psum[i] = 0.0f;
    }
    const int w = t >> 6;
    const int lane = t & 63;
    const int tile = blockIdx.x * 4 + w;
    if (tile >= GEMM_TILES) return;
    const int node0 = tile * 16;
    const int lr = lane & 15;
    const int lg = lane >> 4;

    bf16x8 bw[8][2];
#pragma unroll
    for (int kb = 0; kb < 8; kb++) {
#pragma unroll
        for (int cb = 0; cb < 2; cb++) {
            const uint4 v = wfrag[(kb * 2 + cb) * 64 + lane];
            bw[kb][cb] = *(const bf16x8*)&v;
        }
    }

    const float4* xr = (const float4*)(x + (size_t)(node0 + lr) * IN_CH);
    f32x4 acc0 = {0.f, 0.f, 0.f, 0.f}, acc1 = {0.f, 0.f, 0.f, 0.f};
#pragma unroll
    for (int kb = 0; kb < 8; kb++) {
        const float4 A = xr[kb * 8 + lg * 2];
        const float4 B = xr[kb * 8 + lg * 2 + 1];
        bf16x8 a;
        a[0] = (short)bfr(A.x); a[1] = (short)bfr(A.y);
        a[2] = (short)bfr(A.z); a[3] = (short)bfr(A.w);
        a[4] = (short)bfr(B.x); a[5] = (short)bfr(B.y);
        a[6] = (short)bfr(B.z); a[7] = (short)bfr(B.w);
        acc0 = __builtin_amdgcn_mfma_f32_16x16x32_bf16(a, bw[kb][0], acc0, 0, 0, 0);
        acc1 = __builtin_amdgcn_mfma_f32_16x16x32_bf16(a, bw[kb][1], acc1, 0, 0, 0);
    }

#pragma unroll
    for (int r = 0; r < 4; r++) {
        const int n = node0 + lg * 4 + r;
        const float dv = dinv[n];
        const int pk = __builtin_amdgcn_cvt_pk_fp8_f32(acc0[r] * dv, acc1[r] * dv, 0, false);
        y1f8[(size_t)n * 32 + lr]      = (unsigned char)(pk & 0xff);
        y1f8[(size_t)n * 32 + 16 + lr] = (unsigned char)((pk >> 8) & 0xff);
    }
}

// fused gather+layer2: 4 lanes/node, 8B/lane (fp8), 16 edges in flight.
// y2 written as fp8 (8B row).
__global__ __launch_bounds__(256) void g32l2_kernel(
        const unsigned* __restrict__ rowstart, const unsigned* __restrict__ deg,
        const int* __restrict__ csr, const uint2* __restrict__ y1f8v,
        const float* __restrict__ dinv, const float* __restrict__ b1,
        const float* __restrict__ W2, uint2* __restrict__ y2v2) {
    __shared__ float w2s[HID_CH][9];
    __shared__ float b1s[HID_CH];
    const int t = threadIdx.x;
    { const int k = t >> 3, c = t & 7; w2s[k][c] = W2[t]; }
    if (t < HID_CH) b1s[t] = b1[t];
    __syncthreads();

    const int nl = t >> 2;
    const int q = t & 3;
    const int node = blockIdx.x * 64 + nl;
    if (node >= N_NODES) return;
    const int b4 = (t & 63) & ~3;

    const unsigned d = deg[node];
    const unsigned pd = (d + 7u) & ~7u;
    const unsigned base = rowstart[node];

    float a0 = 0, a1 = 0, a2 = 0, a3 = 0, a4 = 0, a5 = 0, a6 = 0, a7 = 0;
    { const uint2 sv = y1f8v[(size_t)node * 4 + q]; ACC8F8(sv); }

    unsigned j = 0;
    for (; j + 16 <= pd; j += 16) {
        const int4 e4 = ((const int4*)(csr + base + j))[q];
        const int s0  = __shfl(e4.x, b4 + 0);
        const int s1  = __shfl(e4.y, b4 + 0);
        const int s2  = __shfl(e4.z, b4 + 0);
        const int s3  = __shfl(e4.w, b4 + 0);
        const int s4  = __shfl(e4.x, b4 + 1);
        const int s5  = __shfl(e4.y, b4 + 1);
        const int s6  = __shfl(e4.z, b4 + 1);
        const int s7  = __shfl(e4.w, b4 + 1);
        const int s8  = __shfl(e4.x, b4 + 2);
        const int s9  = __shfl(e4.y, b4 + 2);
        const int s10 = __shfl(e4.z, b4 + 2);
        const int s11 = __shfl(e4.w, b4 + 2);
        const int s12 = __shfl(e4.x, b4 + 3);
        const int s13 = __shfl(e4.y, b4 + 3);
        const int s14 = __shfl(e4.z, b4 + 3);
        const int s15 = __shfl(e4.w, b4 + 3);
        const uint2 r0  = y1f8v[(size_t)s0 * 4 + q];
        const uint2 r1  = y1f8v[(size_t)s1 * 4 + q];
        const uint2 r2  = y1f8v[(size_t)s2 * 4 + q];
        const uint2 r3  = y1f8v[(size_t)s3 * 4 + q];
        const uint2 r4  = y1f8v[(size_t)s4 * 4 + q];
        const uint2 r5  = y1f8v[(size_t)s5 * 4 + q];
        const uint2 r6  = y1f8v[(size_t)s6 * 4 + q];
        const uint2 r7  = y1f8v[(size_t)s7 * 4 + q];
        const uint2 r8  = y1f8v[(size_t)s8 * 4 + q];
        const uint2 r9  = y1f8v[(size_t)s9 * 4 + q];
        const uint2 r10 = y1f8v[(size_t)s10 * 4 + q];
        const uint2 r11 = y1f8v[(size_t)s11 * 4 + q];
        const uint2 r12 = y1f8v[(size_t)s12 * 4 + q];
        const uint2 r13 = y1f8v[(size_t)s13 * 4 + q];
        const uint2 r14 = y1f8v[(size_t)s14 * 4 + q];
        const uint2 r15 = y1f8v[(size_t)s15 * 4 + q];
        ACC8F8(r0);  ACC8F8(r1);  ACC8F8(r2);  ACC8F8(r3);
        ACC8F8(r4);  ACC8F8(r5);  ACC8F8(r6);  ACC8F8(r7);
        ACC8F8(r8);  ACC8F8(r9);  ACC8F8(r10); ACC8F8(r11);
        ACC8F8(r12); ACC8F8(r13); ACC8F8(r14); ACC8F8(r15);
    }
    if (j < pd) {
        const int4 e4 = ((const int4*)(csr + base + j))[q & 1];
        const int s0 = __shfl(e4.x, b4);
        const int s1 = __shfl(e4.y, b4);
        const int s2 = __shfl(e4.z, b4);
        const int s3 = __shfl(e4.w, b4);
        const int s4 = __shfl(e4.x, b4 + 1);
        const int s5 = __shfl(e4.y, b4 + 1);
        const int s6 = __shfl(e4.z, b4 + 1);
        const int s7 = __shfl(e4.w, b4 + 1);
        const uint2 r0 = y1f8v[(size_t)s0 * 4 + q];
        const uint2 r1 = y1f8v[(size_t)s1 * 4 + q];
        const uint2 r2 = y1f8v[(size_t)s2 * 4 + q];
        const uint2 r3 = y1f8v[(size_t)s3 * 4 + q];
        const uint2 r4 = y1f8v[(size_t)s4 * 4 + q];
        const uint2 r5 = y1f8v[(size_t)s5 * 4 + q];
        const uint2 r6 = y1f8v[(size_t)s6 * 4 + q];
        const uint2 r7 = y1f8v[(size_t)s7 * 4 + q];
        ACC8F8(r0); ACC8F8(r1); ACC8F8(r2); ACC8F8(r3);
        ACC8F8(r4); ACC8F8(r5); ACC8F8(r6); ACC8F8(r7);
    }

    const float dv = dinv[node];
    float h[8];
    h[0] = fmaxf(fmaf(a0, dv, b1s[8 * q + 0]), 0.0f);
    h[1] = fmaxf(fmaf(a1, dv, b1s[8 * q + 1]), 0.0f);
    h[2] = fmaxf(fmaf(a2, dv, b1s[8 * q + 2]), 0.0f);
    h[3] = fmaxf(fmaf(a3, dv, b1s[8 * q + 3]), 0.0f);
    h[4] = fmaxf(fmaf(a4, dv, b1s[8 * q + 4]), 0.0f);
    h[5] = fmaxf(fmaf(a5, dv, b1s[8 * q + 5]), 0.0f);
    h[6] = fmaxf(fmaf(a6, dv, b1s[8 * q + 6]), 0.0f);
    h[7] = fmaxf(fmaf(a7, dv, b1s[8 * q + 7]), 0.0f);

    float p[8] = {0, 0, 0, 0, 0, 0, 0, 0};
#pragma unroll
    for (int i = 0; i < 8; i++) {
        const float hi = h[i];
#pragma unroll
        for (int c = 0; c < 8; c++) p[c] = fmaf(hi, w2s[8 * q + i][c], p[c]);
    }
#pragma unroll
    for (int c = 0; c < 8; c++) p[c] += __shfl_xor(p[c], 1);
#pragma unroll
    for (int c = 0; c < 8; c++) p[c] += __shfl_xor(p[c], 2);

    if (q == 0) {
        const int pk01 = __builtin_amdgcn_cvt_pk_fp8_f32(p[0] * dv, p[1] * dv, 0, false);
        const int pk23 = __builtin_amdgcn_cvt_pk_fp8_f32(p[2] * dv, p[3] * dv, 0, false);
        const int pk45 = __builtin_amdgcn_cvt_pk_fp8_f32(p[4] * dv, p[5] * dv, 0, false);
        const int pk67 = __builtin_amdgcn_cvt_pk_fp8_f32(p[6] * dv, p[7] * dv, 0, false);
        uint2 pk;
        pk.x = ((unsigned)pk01 & 0xffffu) | (((unsigned)pk23 & 0xffffu) << 16);
        pk.y = ((unsigned)pk45 & 0xffffu) | (((unsigned)pk67 & 0xffffu) << 16);
        y2v2[node] = pk;
    }
}

// fused gather+pool: 8 lanes/node, edge-per-lane fp8 (uint2) loads, 4-deep
// pipeline; shfl butterfly; per-graph LDS accumulators. No device fence.
__global__ __launch_bounds__(256) void g8pool_kernel(
        const unsigned* __restrict__ rowstart, const unsigned* __restrict__ deg,
        const int* __restrict__ csr, const uint2* __restrict__ y2v2,
        const float* __restrict__ dinv, const float* __restrict__ b2,
        const int* __restrict__ batch,
        float* __restrict__ psum, float* __restrict__ pcnt) {
    __shared__ float ls[N_GRAPHS * OUT_CH];
    __shared__ float lc[N_GRAPHS];
    __shared__ float b2s[OUT_CH];
    __shared__ int grange[2];
    const int t = threadIdx.x;
    ls[t] = 0.0f; ls[t + 256] = 0.0f;
    if (t < N_GRAPHS) lc[t] = 0.0f;
    if (t < OUT_CH) b2s[t] = b2[t];
    if (t == 0) { grange[0] = N_GRAPHS; grange[1] = -1; }
    __syncthreads();

    const int nl = t >> 3;
    const int l = t & 7;
    const int node = blockIdx.x * 32 + nl;
    const int g = batch[node];
    const unsigned d = deg[node];
    const unsigned pd = (d + 7u) & ~7u;
    const unsigned base = rowstart[node];

    float a0 = 0, a1 = 0, a2 = 0, a3 = 0, a4 = 0, a5 = 0, a6 = 0, a7 = 0;
    if (l == 0) { const uint2 sv = y2v2[node]; ACC8F8(sv); }
    unsigned j = 0;
    for (; j + 32 <= pd; j += 32) {
        const int sa = csr[base + j + l];
        const int sb = csr[base + j + 8 + l];
        const int sc2 = csr[base + j + 16 + l];
        const int sd = csr[base + j + 24 + l];
        const uint2 ra = y2v2[sa];
        const uint2 rb = y2v2[sb];
        const uint2 rc = y2v2[sc2];
        const uint2 rd = y2v2[sd];
        ACC8F8(ra); ACC8F8(rb); ACC8F8(rc); ACC8F8(rd);
    }
    for (; j + 16 <= pd; j += 16) {
        const int sa = csr[base + j + l];
        const int sb = csr[base + j + 8 + l];
        const uint2 ra = y2v2[sa];
        const uint2 rb = y2v2[sb];
        ACC8F8(ra); ACC8F8(rb);
    }
    if (j < pd) {
        const int sa = csr[base + j + l];
        const uint2 ra = y2v2[sa];
        ACC8F8(ra);
    }
    a0 += __shfl_xor(a0, 1); a1 += __shfl_xor(a1, 1); a2 += __shfl_xor(a2, 1);
    a3 += __shfl_xor(a3, 1); a4 += __shfl_xor(a4, 1); a5 += __shfl_xor(a5, 1);
    a6 += __shfl_xor(a6, 1); a7 += __shfl_xor(a7, 1);
    a0 += __shfl_xor(a0, 2); a1 += __shfl_xor(a1, 2); a2 += __shfl_xor(a2, 2);
    a3 += __shfl_xor(a3, 2); a4 += __shfl_xor(a4, 2); a5 += __shfl_xor(a5, 2);
    a6 += __shfl_xor(a6, 2); a7 += __shfl_xor(a7, 2);
    a0 += __shfl_xor(a0, 4); a1 += __shfl_xor(a1, 4); a2 += __shfl_xor(a2, 4);
    a3 += __shfl_xor(a3, 4); a4 += __shfl_xor(a4, 4); a5 += __shfl_xor(a5, 4);
    a6 += __shfl_xor(a6, 4); a7 += __shfl_xor(a7, 4);
    const float sc = (l < 4) ? ((l < 2) ? (l == 0 ? a0 : a1) : (l == 2 ? a2 : a3))
                             : ((l < 6) ? (l == 4 ? a4 : a5) : (l == 6 ? a6 : a7));

    const float o = fmaxf(fmaf(sc, dinv[node], b2s[l]), 0.0f);
    atomicAdd(&ls[g * OUT_CH + l], o);
    if (l == 0) {
        atomicAdd(&lc[g], 1.0f);
        atomicMin(&grange[0], g);
        atomicMax(&grange[1], g);
    }
    __syncthreads();
    const int g0 = grange[0], g1 = grange[1];
    const int nent = (g1 - g0 + 1) * OUT_CH;
    for (int i = t; i < nent; i += 256)
        atomicAdd(&psum[g0 * OUT_CH + i], ls[g0 * OUT_CH + i]);
    for (int i = t; i < g1 - g0 + 1; i += 256)
        atomicAdd(&pcnt[g0 + i], lc[g0 + i]);
}

__global__ void logsoftmax_kernel(const float* __restrict__ psum,
                                  const float* __restrict__ pcnt,
                                  float* __restrict__ out) {
    const int g = threadIdx.x;
    if (g >= N_GRAPHS) return;
    const float cnt = fmaxf(pcnt[g], 1.0f);
    float p[OUT_CH];
    float m = -INFINITY;
#pragma unroll
    for (int c = 0; c < OUT_CH; c++) {
        p[c] = psum[g * OUT_CH + c] / cnt;
        m = fmaxf(m, p[c]);
    }
    float s = 0.0f;
#pragma unroll
    for (int c = 0; c < OUT_CH; c++) s += expf(p[c] - m);
    const float lse = logf(s);
#pragma unroll
    for (int c = 0; c < OUT_CH; c++) out[g * OUT_CH + c] = p[c] - m - lse;
}

extern "C" void kernel_launch(void* const* d_in, const int* in_sizes, int n_in,
                              void* d_out, int out_size, void* d_ws, size_t ws_size,
                              hipStream_t stream) {
    const float* x    = (const float*)d_in[0];
    const int* eidx   = (const int*)d_in[1];
    const int* batch  = (const int*)d_in[2];
    const float* W1   = (const float*)d_in[3];
    const float* b1   = (const float*)d_in[4];
    const float* W2   = (const float*)d_in[5];
    const float* b2   = (const float*)d_in[6];
    float* out = (float*)d_out;

    const int* src = eidx;
    const int* dst = eidx + N_EDGES;

    char* wsb = (char*)d_ws;
    unsigned* deg   = (unsigned*)(wsb) + OFF_DEG;
    float*    dinv  = (float*)(wsb) + OFF_DINV;
    unsigned* rows  = (unsigned*)(wsb) + OFF_ROWS;
    unsigned* cntg  = (unsigned*)(wsb) + OFF_CNTG;
    int*      csr   = (int*)(wsb) + OFF_CSR;
    unsigned* y1w   = (unsigned*)(wsb) + OFF_Y1;
    unsigned* bbuf  = (unsigned*)(wsb) + OFF_BBUF;
    unsigned* y2w   = (unsigned*)(wsb) + OFF_Y2;
    float*    psum  = (float*)(wsb) + OFF_PSUM;
    float*    pcnt  = (float*)(wsb) + OFF_PCNT;
    uint4*    wfrag = (uint4*)((unsigned*)(wsb) + OFF_WFRAG);

    wprep_kernel<<<4, 256, 0, stream>>>(W1, wfrag, cntg, y1w, y2w);
    p1_partition<<<NBLK_P1, 256, 0, stream>>>(src, dst, cntg, bbuf);
    p2_build<<<NBUCK, 256, 0, stream>>>(cntg, bbuf, csr, deg, rows, dinv);
    gemm1_kernel<<<GEMM_BLKS, 256, 0, stream>>>(x, wfrag, dinv, (unsigned char*)y1w, psum);
    g32l2_kernel<<<(N_NODES + 63) / 64, 256, 0, stream>>>(rows, deg, csr, (const uint2*)y1w,
                                                          dinv, b1, W2, (uint2*)y2w);
    g8pool_kernel<<<POOL_BLKS, 256, 0, stream>>>(rows, deg, csr, (const uint2*)y2w,
                                                 dinv, b2, batch, psum, pcnt);
    logsoftmax_kernel<<<1, 64, 0, stream>>>(psum, pcnt, out);
}

// Round 22
// 111.201 us; speedup vs baseline: 1.0249x; 1.0249x over previous
//
#include <hip/hip_runtime.h>
#include <hip/hip_bf16.h>
#include <math.h>

#define N_NODES 100000
#define N_EDGES 1600000
#define IN_CH 256
#define HID_CH 32
#define OUT_CH 8
#define N_GRAPHS 64

// bucket sort params (128 nodes / bucket)
#define BUCK_SHIFT 7
#define NODES_PER_BUCK 128
#define NBUCK ((N_NODES + NODES_PER_BUCK - 1) / NODES_PER_BUCK)   // 782
#define CAP 2560
#define PCAP 3456
#define CHUNK 4096
#define NBLK_P1 ((N_EDGES + CHUNK - 1) / CHUNK)                   // 391
#define ARENA (NBUCK * CAP)

#define DUMMY_ROW N_NODES
#define Y_ROWS 100008

#define GEMM_TILES (N_NODES / 16)          // 6250
#define GEMM_BLKS ((GEMM_TILES + 3) / 4)   // 1563
#define POOL_BLKS (N_NODES / 32)           // 3125

// ---------------- workspace layout (in 4-byte words) ----------------
#define OFF_DEG    0
#define OFF_DINV   (OFF_DEG + N_NODES)
#define OFF_ROWS   (OFF_DINV + N_NODES)
#define OFF_CNTG   (OFF_ROWS + N_NODES)
#define OFF_CSR    (OFF_CNTG + 784)
#define OFF_Y1     (OFF_CSR + NBUCK*PCAP)           // fp8[Y_ROWS*32] = 8 words/row
#define OFF_BBUF   (OFF_Y1 + Y_ROWS*8)
#define OFF_Y2     (OFF_BBUF + ARENA)               // bf16[Y_ROWS*8] = 4 words/row
#define OFF_PSUM   (OFF_Y2 + Y_ROWS*4)
#define OFF_PCNT   (OFF_PSUM + N_GRAPHS*OUT_CH)
#define OFF_WFRAG  (OFF_PCNT + 128)                 // 4096 words

typedef __attribute__((ext_vector_type(8))) short bf16x8;
typedef __attribute__((ext_vector_type(4))) float f32x4;
typedef __attribute__((ext_vector_type(2))) float f32x2;

__device__ __forceinline__ unsigned bfr(float f) {
    unsigned u = __float_as_uint(f);
    return (u + 0x7fffu + ((u >> 16) & 1u)) >> 16;
}
__device__ __forceinline__ float bf_lo(unsigned w) { return __uint_as_float(w << 16); }
__device__ __forceinline__ float bf_hi(unsigned w) { return __uint_as_float(w & 0xffff0000u); }

#define ACC8(r) do { \
    a0 += bf_lo((r).x); a1 += bf_hi((r).x); a2 += bf_lo((r).y); a3 += bf_hi((r).y); \
    a4 += bf_lo((r).z); a5 += bf_hi((r).z); a6 += bf_lo((r).w); a7 += bf_hi((r).w); } while (0)

// accumulate 8 fp8 channels from a uint2 (bytes 0..7 = ch 8q+0..7)
#define ACC8F8(v) do { \
    const f32x2 q0 = __builtin_amdgcn_cvt_pk_f32_fp8((int)(v).x, false); \
    const f32x2 q1 = __builtin_amdgcn_cvt_pk_f32_fp8((int)(v).x, true);  \
    const f32x2 q2 = __builtin_amdgcn_cvt_pk_f32_fp8((int)(v).y, false); \
    const f32x2 q3 = __builtin_amdgcn_cvt_pk_f32_fp8((int)(v).y, true);  \
    a0 += q0.x; a1 += q0.y; a2 += q1.x; a3 += q1.y; \
    a4 += q2.x; a5 += q2.y; a6 += q3.x; a7 += q3.y; } while (0)

// wprep: pack W1 into MFMA B-frags; block 0 zeroes cntg + dummy rows.
__global__ __launch_bounds__(256) void wprep_kernel(
        const float* __restrict__ W1, uint4* __restrict__ wfrag,
        unsigned* __restrict__ cntg, unsigned* __restrict__ y1w,
        unsigned* __restrict__ y2w) {
    const int t = threadIdx.x;
    if (blockIdx.x == 0) {
        for (int i = t; i < NBUCK; i += 256) cntg[i] = 0u;
        if (t < 8) y1w[(size_t)DUMMY_ROW * 8 + t] = 0u;   // fp8 row = 32B
        if (t < 4) y2w[(size_t)DUMMY_ROW * 4 + t] = 0u;
    }
    const int fl = blockIdx.x * 256 + t;
    const int f = fl >> 6, lane = fl & 63;
    const int kb = f >> 1, cb = f & 1;
    const int lr = lane & 15, lg = lane >> 4;
    unsigned short s[8];
#pragma unroll
    for (int j = 0; j < 8; j++)
        s[j] = (unsigned short)bfr(W1[(kb * 32 + lg * 8 + j) * 32 + cb * 16 + lr]);
    uint4 pk;
    pk.x = s[0] | ((unsigned)s[1] << 16);
    pk.y = s[2] | ((unsigned)s[3] << 16);
    pk.z = s[4] | ((unsigned)s[5] << 16);
    pk.w = s[6] | ((unsigned)s[7] << 16);
    wfrag[fl] = pk;
}

// p1: CHUNK=4096 (391 blocks) -> half the cntg atomic contention and
// scattered-write line touches vs CHUNK=2048. 16 edges staged per thread.
__global__ __launch_bounds__(256) void p1_partition(
        const int* __restrict__ src, const int* __restrict__ dst,
        unsigned* __restrict__ cntg, unsigned* __restrict__ bbuf) {
    __shared__ unsigned hcnt[NBUCK];
    __shared__ unsigned hcur[NBUCK];
    const int t = threadIdx.x;
    const long long e0 = (long long)blockIdx.x * CHUNK;

    int rs[16]; unsigned rd[16];
#pragma unroll
    for (int i = 0; i < 16; i++) {
        const long long e = e0 + t + i * 256;
        const bool v = (e < N_EDGES);
        rs[i] = v ? src[e] : 0;
        rd[i] = v ? (unsigned)dst[e] : 0xFFFFFFFFu;
    }
    for (int i = t; i < NBUCK; i += 256) hcnt[i] = 0;
    __syncthreads();
#pragma unroll
    for (int i = 0; i < 16; i++)
        if (rd[i] != 0xFFFFFFFFu) atomicAdd(&hcnt[rd[i] >> BUCK_SHIFT], 1u);
    __syncthreads();
    for (int i = t; i < NBUCK; i += 256) {
        const unsigned c = hcnt[i];
        const unsigned r = c ? atomicAdd(&cntg[i], c) : 0u;
        hcur[i] = (unsigned)i * CAP + r;
    }
    __syncthreads();
#pragma unroll
    for (int i = 0; i < 16; i++) {
        if (rd[i] != 0xFFFFFFFFu) {
            const unsigned b = rd[i] >> BUCK_SHIFT;
            const unsigned pos = atomicAdd(&hcur[b], 1u);
            if (pos - b * CAP < CAP)
                bbuf[pos] = (unsigned)rs[i] | ((rd[i] & (NODES_PER_BUCK - 1)) << 17);
        }
    }
}

__global__ __launch_bounds__(256) void p2_build(
        const unsigned* __restrict__ cntg,
        const unsigned* __restrict__ bbuf, int* __restrict__ csr,
        unsigned* __restrict__ deg, unsigned* __restrict__ rowstart,
        float* __restrict__ dinv) {
    __shared__ unsigned hist[NODES_PER_BUCK];
    __shared__ unsigned start[NODES_PER_BUCK];
    __shared__ unsigned cur[NODES_PER_BUCK];
    __shared__ unsigned s[256];
    __shared__ int lcsr[PCAP];
    const int b = blockIdx.x;
    const int t = threadIdx.x;
    unsigned cnt = cntg[b]; if (cnt > CAP) cnt = CAP;
    const unsigned* mybuf = bbuf + (size_t)b * CAP;

    if (t < NODES_PER_BUCK) hist[t] = 0;
    __syncthreads();
    for (unsigned i = t; i < cnt; i += 256) atomicAdd(&hist[mybuf[i] >> 17], 1u);
    __syncthreads();
    const unsigned d = (t < NODES_PER_BUCK) ? hist[t] : 0u;
    const unsigned pd = (d + 7u) & ~7u;
    s[t] = pd;
    __syncthreads();
    for (int off = 1; off < 256; off <<= 1) {
        unsigned x = (t >= off) ? s[t - off] : 0u;
        __syncthreads();
        s[t] += x;
        __syncthreads();
    }
    const unsigned total = s[255];
    const unsigned ex = s[t] - pd;
    if (t < NODES_PER_BUCK) { start[t] = ex; cur[t] = ex; }
    __syncthreads();
    for (unsigned i = t; i < total; i += 256) lcsr[i] = DUMMY_ROW;
    __syncthreads();
    for (unsigned i = t; i < cnt; i += 256) {
        const unsigned p = mybuf[i];
        const unsigned pos = atomicAdd(&cur[p >> 17], 1u);
        lcsr[pos] = (int)(p & 0x1FFFFu);
    }
    __syncthreads();
    const unsigned gbase = (unsigned)b * PCAP;
    for (unsigned i = t; i < total; i += 256) csr[gbase + i] = lcsr[i];
    const int n = b * NODES_PER_BUCK + t;
    if (t < NODES_PER_BUCK && n < N_NODES) {
        deg[n] = d;
        rowstart[n] = gbase + start[t];
        dinv[n] = rsqrtf((float)d + 1.0f);
    }
}

// y1 = fp8_e4m3((x @ W1) * dinv) via MFMA 16x16x32 bf16 — no LDS/barriers.
// fp8 rows (32B) make y1 3.2 MB -> fits per-XCD L2 -> gather hits.
__global__ __launch_bounds__(256) void gemm1_kernel(
        const float* __restrict__ x, const uint4* __restrict__ wfrag,
        const float* __restrict__ dinv, unsigned char* __restrict__ y1f8,
        float* __restrict__ psum) {
    const int t = threadIdx.x;
    if (blockIdx.x == 0) {
        for (int i = t; i < N_GRAPHS * OUT_CH + N_GRAPHS; i += 256) psum[i] = 0.0f;
    }
    const int w = t >> 6;
    const int lane = t & 63;
    const int tile = blockIdx.x * 4 + w;
    if (tile >= GEMM_TILES) return;
    const int node0 = tile * 16;
    const int lr = lane & 15;
    const int lg = lane >> 4;

    bf16x8 bw[8][2];
#pragma unroll
    for (int kb = 0; kb < 8; kb++) {
#pragma unroll
        for (int cb = 0; cb < 2; cb++) {
            const uint4 v = wfrag[(kb * 2 + cb) * 64 + lane];
            bw[kb][cb] = *(const bf16x8*)&v;
        }
    }

    const float4* xr = (const float4*)(x + (size_t)(node0 + lr) * IN_CH);
    f32x4 acc0 = {0.f, 0.f, 0.f, 0.f}, acc1 = {0.f, 0.f, 0.f, 0.f};
#pragma unroll
    for (int kb = 0; kb < 8; kb++) {
        const float4 A = xr[kb * 8 + lg * 2];
        const float4 B = xr[kb * 8 + lg * 2 + 1];
        bf16x8 a;
        a[0] = (short)bfr(A.x); a[1] = (short)bfr(A.y);
        a[2] = (short)bfr(A.z); a[3] = (short)bfr(A.w);
        a[4] = (short)bfr(B.x); a[5] = (short)bfr(B.y);
        a[6] = (short)bfr(B.z); a[7] = (short)bfr(B.w);
        acc0 = __builtin_amdgcn_mfma_f32_16x16x32_bf16(a, bw[kb][0], acc0, 0, 0, 0);
        acc1 = __builtin_amdgcn_mfma_f32_16x16x32_bf16(a, bw[kb][1], acc1, 0, 0, 0);
    }

    // epilogue: row n bytes [0..15]=ch0-15 (acc0), [16..31]=ch16-31 (acc1)
#pragma unroll
    for (int r = 0; r < 4; r++) {
        const int n = node0 + lg * 4 + r;
        const float dv = dinv[n];
        const int pk = __builtin_amdgcn_cvt_pk_fp8_f32(acc0[r] * dv, acc1[r] * dv, 0, false);
        y1f8[(size_t)n * 32 + lr]      = (unsigned char)(pk & 0xff);
        y1f8[(size_t)n * 32 + 16 + lr] = (unsigned char)((pk >> 8) & 0xff);
    }
}

// fused gather+layer2: 4 lanes/node, 8B/lane (fp8), 16 edges in flight.
__global__ __launch_bounds__(256) void g32l2_kernel(
        const unsigned* __restrict__ rowstart, const unsigned* __restrict__ deg,
        const int* __restrict__ csr, const uint2* __restrict__ y1f8v,
        const float* __restrict__ dinv, const float* __restrict__ b1,
        const float* __restrict__ W2, uint4* __restrict__ y2v4) {
    __shared__ float w2s[HID_CH][9];
    __shared__ float b1s[HID_CH];
    const int t = threadIdx.x;
    { const int k = t >> 3, c = t & 7; w2s[k][c] = W2[t]; }
    if (t < HID_CH) b1s[t] = b1[t];
    __syncthreads();

    const int nl = t >> 2;
    const int q = t & 3;
    const int node = blockIdx.x * 64 + nl;
    if (node >= N_NODES) return;
    const int b4 = (t & 63) & ~3;

    const unsigned d = deg[node];
    const unsigned pd = (d + 7u) & ~7u;
    const unsigned base = rowstart[node];

    float a0 = 0, a1 = 0, a2 = 0, a3 = 0, a4 = 0, a5 = 0, a6 = 0, a7 = 0;
    { const uint2 sv = y1f8v[(size_t)node * 4 + q]; ACC8F8(sv); }

    unsigned j = 0;
    for (; j + 16 <= pd; j += 16) {
        const int4 e4 = ((const int4*)(csr + base + j))[q];
        const int s0  = __shfl(e4.x, b4 + 0);
        const int s1  = __shfl(e4.y, b4 + 0);
        const int s2  = __shfl(e4.z, b4 + 0);
        const int s3  = __shfl(e4.w, b4 + 0);
        const int s4  = __shfl(e4.x, b4 + 1);
        const int s5  = __shfl(e4.y, b4 + 1);
        const int s6  = __shfl(e4.z, b4 + 1);
        const int s7  = __shfl(e4.w, b4 + 1);
        const int s8  = __shfl(e4.x, b4 + 2);
        const int s9  = __shfl(e4.y, b4 + 2);
        const int s10 = __shfl(e4.z, b4 + 2);
        const int s11 = __shfl(e4.w, b4 + 2);
        const int s12 = __shfl(e4.x, b4 + 3);
        const int s13 = __shfl(e4.y, b4 + 3);
        const int s14 = __shfl(e4.z, b4 + 3);
        const int s15 = __shfl(e4.w, b4 + 3);
        const uint2 r0  = y1f8v[(size_t)s0 * 4 + q];
        const uint2 r1  = y1f8v[(size_t)s1 * 4 + q];
        const uint2 r2  = y1f8v[(size_t)s2 * 4 + q];
        const uint2 r3  = y1f8v[(size_t)s3 * 4 + q];
        const uint2 r4  = y1f8v[(size_t)s4 * 4 + q];
        const uint2 r5  = y1f8v[(size_t)s5 * 4 + q];
        const uint2 r6  = y1f8v[(size_t)s6 * 4 + q];
        const uint2 r7  = y1f8v[(size_t)s7 * 4 + q];
        const uint2 r8  = y1f8v[(size_t)s8 * 4 + q];
        const uint2 r9  = y1f8v[(size_t)s9 * 4 + q];
        const uint2 r10 = y1f8v[(size_t)s10 * 4 + q];
        const uint2 r11 = y1f8v[(size_t)s11 * 4 + q];
        const uint2 r12 = y1f8v[(size_t)s12 * 4 + q];
        const uint2 r13 = y1f8v[(size_t)s13 * 4 + q];
        const uint2 r14 = y1f8v[(size_t)s14 * 4 + q];
        const uint2 r15 = y1f8v[(size_t)s15 * 4 + q];
        ACC8F8(r0);  ACC8F8(r1);  ACC8F8(r2);  ACC8F8(r3);
        ACC8F8(r4);  ACC8F8(r5);  ACC8F8(r6);  ACC8F8(r7);
        ACC8F8(r8);  ACC8F8(r9);  ACC8F8(r10); ACC8F8(r11);
        ACC8F8(r12); ACC8F8(r13); ACC8F8(r14); ACC8F8(r15);
    }
    if (j < pd) {
        const int4 e4 = ((const int4*)(csr + base + j))[q & 1];
        const int s0 = __shfl(e4.x, b4);
        const int s1 = __shfl(e4.y, b4);
        const int s2 = __shfl(e4.z, b4);
        const int s3 = __shfl(e4.w, b4);
        const int s4 = __shfl(e4.x, b4 + 1);
        const int s5 = __shfl(e4.y, b4 + 1);
        const int s6 = __shfl(e4.z, b4 + 1);
        const int s7 = __shfl(e4.w, b4 + 1);
        const uint2 r0 = y1f8v[(size_t)s0 * 4 + q];
        const uint2 r1 = y1f8v[(size_t)s1 * 4 + q];
        const uint2 r2 = y1f8v[(size_t)s2 * 4 + q];
        const uint2 r3 = y1f8v[(size_t)s3 * 4 + q];
        const uint2 r4 = y1f8v[(size_t)s4 * 4 + q];
        const uint2 r5 = y1f8v[(size_t)s5 * 4 + q];
        const uint2 r6 = y1f8v[(size_t)s6 * 4 + q];
        const uint2 r7 = y1f8v[(size_t)s7 * 4 + q];
        ACC8F8(r0); ACC8F8(r1); ACC8F8(r2); ACC8F8(r3);
        ACC8F8(r4); ACC8F8(r5); ACC8F8(r6); ACC8F8(r7);
    }

    const float dv = dinv[node];
    float h[8];
    h[0] = fmaxf(fmaf(a0, dv, b1s[8 * q + 0]), 0.0f);
    h[1] = fmaxf(fmaf(a1, dv, b1s[8 * q + 1]), 0.0f);
    h[2] = fmaxf(fmaf(a2, dv, b1s[8 * q + 2]), 0.0f);
    h[3] = fmaxf(fmaf(a3, dv, b1s[8 * q + 3]), 0.0f);
    h[4] = fmaxf(fmaf(a4, dv, b1s[8 * q + 4]), 0.0f);
    h[5] = fmaxf(fmaf(a5, dv, b1s[8 * q + 5]), 0.0f);
    h[6] = fmaxf(fmaf(a6, dv, b1s[8 * q + 6]), 0.0f);
    h[7] = fmaxf(fmaf(a7, dv, b1s[8 * q + 7]), 0.0f);

    float p[8] = {0, 0, 0, 0, 0, 0, 0, 0};
#pragma unroll
    for (int i = 0; i < 8; i++) {
        const float hi = h[i];
#pragma unroll
        for (int c = 0; c < 8; c++) p[c] = fmaf(hi, w2s[8 * q + i][c], p[c]);
    }
#pragma unroll
    for (int c = 0; c < 8; c++) p[c] += __shfl_xor(p[c], 1);
#pragma unroll
    for (int c = 0; c < 8; c++) p[c] += __shfl_xor(p[c], 2);

    if (q == 0) {
        uint4 pk;
        pk.x = bfr(p[0] * dv) | (bfr(p[1] * dv) << 16);
        pk.y = bfr(p[2] * dv) | (bfr(p[3] * dv) << 16);
        pk.z = bfr(p[4] * dv) | (bfr(p[5] * dv) << 16);
        pk.w = bfr(p[6] * dv) | (bfr(p[7] * dv) << 16);
        y2v4[node] = pk;
    }
}

// fused gather+pool: 8 lanes/node, edge-per-lane uint4 loads, 2x unrolled;
// shfl butterfly; per-graph LDS accumulators. No device fence (R17 lesson).
__global__ __launch_bounds__(256) void g8pool_kernel(
        const unsigned* __restrict__ rowstart, const unsigned* __restrict__ deg,
        const int* __restrict__ csr, const uint4* __restrict__ y2v4,
        const float* __restrict__ dinv, const float* __restrict__ b2,
        const int* __restrict__ batch,
        float* __restrict__ psum, float* __restrict__ pcnt) {
    __shared__ float ls[N_GRAPHS * OUT_CH];
    __shared__ float lc[N_GRAPHS];
    __shared__ float b2s[OUT_CH];
    __shared__ int grange[2];
    const int t = threadIdx.x;
    ls[t] = 0.0f; ls[t + 256] = 0.0f;
    if (t < N_GRAPHS) lc[t] = 0.0f;
    if (t < OUT_CH) b2s[t] = b2[t];
    if (t == 0) { grange[0] = N_GRAPHS; grange[1] = -1; }
    __syncthreads();

    const int nl = t >> 3;
    const int l = t & 7;
    const int node = blockIdx.x * 32 + nl;
    const int g = batch[node];
    const unsigned d = deg[node];
    const unsigned pd = (d + 7u) & ~7u;
    const unsigned base = rowstart[node];

    float a0 = 0, a1 = 0, a2 = 0, a3 = 0, a4 = 0, a5 = 0, a6 = 0, a7 = 0;
    if (l == 0) { const uint4 sv = y2v4[node]; ACC8(sv); }
    unsigned j = 0;
    for (; j + 16 <= pd; j += 16) {
        const int sa = csr[base + j + l];
        const int sb = csr[base + j + 8 + l];
        const uint4 ra = y2v4[sa];
        const uint4 rb = y2v4[sb];
        ACC8(ra); ACC8(rb);
    }
    if (j < pd) {
        const int sa = csr[base + j + l];
        const uint4 ra = y2v4[sa];
        ACC8(ra);
    }
    a0 += __shfl_xor(a0, 1); a1 += __shfl_xor(a1, 1); a2 += __shfl_xor(a2, 1);
    a3 += __shfl_xor(a3, 1); a4 += __shfl_xor(a4, 1); a5 += __shfl_xor(a5, 1);
    a6 += __shfl_xor(a6, 1); a7 += __shfl_xor(a7, 1);
    a0 += __shfl_xor(a0, 2); a1 += __shfl_xor(a1, 2); a2 += __shfl_xor(a2, 2);
    a3 += __shfl_xor(a3, 2); a4 += __shfl_xor(a4, 2); a5 += __shfl_xor(a5, 2);
    a6 += __shfl_xor(a6, 2); a7 += __shfl_xor(a7, 2);
    a0 += __shfl_xor(a0, 4); a1 += __shfl_xor(a1, 4); a2 += __shfl_xor(a2, 4);
    a3 += __shfl_xor(a3, 4); a4 += __shfl_xor(a4, 4); a5 += __shfl_xor(a5, 4);
    a6 += __shfl_xor(a6, 4); a7 += __shfl_xor(a7, 4);
    const float sc = (l < 4) ? ((l < 2) ? (l == 0 ? a0 : a1) : (l == 2 ? a2 : a3))
                             : ((l < 6) ? (l == 4 ? a4 : a5) : (l == 6 ? a6 : a7));

    const float o = fmaxf(fmaf(sc, dinv[node], b2s[l]), 0.0f);
    atomicAdd(&ls[g * OUT_CH + l], o);
    if (l == 0) {
        atomicAdd(&lc[g], 1.0f);
        atomicMin(&grange[0], g);
        atomicMax(&grange[1], g);
    }
    __syncthreads();
    const int g0 = grange[0], g1 = grange[1];
    const int nent = (g1 - g0 + 1) * OUT_CH;
    for (int i = t; i < nent; i += 256)
        atomicAdd(&psum[g0 * OUT_CH + i], ls[g0 * OUT_CH + i]);
    for (int i = t; i < g1 - g0 + 1; i += 256)
        atomicAdd(&pcnt[g0 + i], lc[g0 + i]);
}

__global__ void logsoftmax_kernel(const float* __restrict__ psum,
                                  const float* __restrict__ pcnt,
                                  float* __restrict__ out) {
    const int g = threadIdx.x;
    if (g >= N_GRAPHS) return;
    const float cnt = fmaxf(pcnt[g], 1.0f);
    float p[OUT_CH];
    float m = -INFINITY;
#pragma unroll
    for (int c = 0; c < OUT_CH; c++) {
        p[c] = psum[g * OUT_CH + c] / cnt;
        m = fmaxf(m, p[c]);
    }
    float s = 0.0f;
#pragma unroll
    for (int c = 0; c < OUT_CH; c++) s += expf(p[c] - m);
    const float lse = logf(s);
#pragma unroll
    for (int c = 0; c < OUT_CH; c++) out[g * OUT_CH + c] = p[c] - m - lse;
}

extern "C" void kernel_launch(void* const* d_in, const int* in_sizes, int n_in,
                              void* d_out, int out_size, void* d_ws, size_t ws_size,
                              hipStream_t stream) {
    const float* x    = (const float*)d_in[0];
    const int* eidx   = (const int*)d_in[1];
    const int* batch  = (const int*)d_in[2];
    const float* W1   = (const float*)d_in[3];
    const float* b1   = (const float*)d_in[4];
    const float* W2   = (const float*)d_in[5];
    const float* b2   = (const float*)d_in[6];
    float* out = (float*)d_out;

    const int* src = eidx;
    const int* dst = eidx + N_EDGES;

    char* wsb = (char*)d_ws;
    unsigned* deg   = (unsigned*)(wsb) + OFF_DEG;
    float*    dinv  = (float*)(wsb) + OFF_DINV;
    unsigned* rows  = (unsigned*)(wsb) + OFF_ROWS;
    unsigned* cntg  = (unsigned*)(wsb) + OFF_CNTG;
    int*      csr   = (int*)(wsb) + OFF_CSR;
    unsigned* y1w   = (unsigned*)(wsb) + OFF_Y1;
    unsigned* bbuf  = (unsigned*)(wsb) + OFF_BBUF;
    unsigned* y2w   = (unsigned*)(wsb) + OFF_Y2;
    float*    psum  = (float*)(wsb) + OFF_PSUM;
    float*    pcnt  = (float*)(wsb) + OFF_PCNT;
    uint4*    wfrag = (uint4*)((unsigned*)(wsb) + OFF_WFRAG);

    wprep_kernel<<<4, 256, 0, stream>>>(W1, wfrag, cntg, y1w, y2w);
    p1_partition<<<NBLK_P1, 256, 0, stream>>>(src, dst, cntg, bbuf);
    p2_build<<<NBUCK, 256, 0, stream>>>(cntg, bbuf, csr, deg, rows, dinv);
    gemm1_kernel<<<GEMM_BLKS, 256, 0, stream>>>(x, wfrag, dinv, (unsigned char*)y1w, psum);
    g32l2_kernel<<<(N_NODES + 63) / 64, 256, 0, stream>>>(rows, deg, csr, (const uint2*)y1w,
                                                          dinv, b1, W2, (uint4*)y2w);
    g8pool_kernel<<<POOL_BLKS, 256, 0, stream>>>(rows, deg, csr, (const uint4*)y2w,
                                                 dinv, b2, batch, psum, pcnt);
    logsoftmax_kernel<<<1, 64, 0, stream>>>(psum, pcnt, out);
}